// Round 5
// baseline (456.174 us; speedup 1.0000x reference)
//
#include <hip/hip_runtime.h>
#include <hip/hip_bf16.h>
#include <math.h>

#define S_LEN 1024
#define HIDN  1024
#define NHEAD 16
#define HDIM  64
#define BATCH 4
#define MTOT  (BATCH * S_LEN)   // 4096

typedef __attribute__((ext_vector_type(8))) short          bf16v8;
typedef __attribute__((ext_vector_type(8))) unsigned short u16v8;
typedef __attribute__((ext_vector_type(4))) unsigned short u16v4;
typedef __attribute__((ext_vector_type(4))) float          f32v4;

// ---------------------------------------------------------------------------
// bf16 hi/lo split helpers (RNE)
// ---------------------------------------------------------------------------
__device__ __forceinline__ unsigned short f2bf_rne(float x) {
    unsigned int u = __float_as_uint(x);
    unsigned int r = (u + 0x7fffu + ((u >> 16) & 1u)) >> 16;
    return (unsigned short)r;
}
__device__ __forceinline__ float bf2f(unsigned short h) {
    return __uint_as_float(((unsigned int)h) << 16);
}
__device__ __forceinline__ void split2(float x, unsigned short& h, unsigned short& l) {
    h = f2bf_rne(x);
    l = f2bf_rne(x - bf2f(h));
}

// ---------------------------------------------------------------------------
// split_a: row-major f32 [M][1024] -> Ah, Al bf16 (same layout).
// ---------------------------------------------------------------------------
__global__ __launch_bounds__(256) void split_a(
    const float* __restrict__ X, unsigned short* __restrict__ H,
    unsigned short* __restrict__ L)
{
    const int i = blockIdx.x * 256 + threadIdx.x;
    const float4 x0 = ((const float4*)X)[2 * i];
    const float4 x1 = ((const float4*)X)[2 * i + 1];
    float xs[8] = {x0.x, x0.y, x0.z, x0.w, x1.x, x1.y, x1.z, x1.w};
    u16v8 h, l;
#pragma unroll
    for (int j = 0; j < 8; ++j) {
        unsigned short hh, ll;
        split2(xs[j], hh, ll);
        h[j] = hh; l[j] = ll;
    }
    ((u16v8*)H)[i] = h;
    ((u16v8*)L)[i] = l;
}

// ---------------------------------------------------------------------------
// split_w: W f32 [K=1024][N=1024] -> transposed Ht, Lt bf16 [N][K] (k-contig).
// ---------------------------------------------------------------------------
__global__ __launch_bounds__(256) void split_w(
    const float* __restrict__ W, unsigned short* __restrict__ H,
    unsigned short* __restrict__ L)
{
    __shared__ float T[64][65];
    const int t  = threadIdx.x;
    const int k0 = blockIdx.y * 64;
    const int n0 = blockIdx.x * 64;

    const int r = t >> 4;
    const int c = (t & 15) * 4;
#pragma unroll
    for (int i = 0; i < 4; ++i) {
        const int rr = r + i * 16;
        const float4 v = *(const float4*)&W[(size_t)(k0 + rr) * 1024 + n0 + c];
        T[rr][c + 0] = v.x; T[rr][c + 1] = v.y;
        T[rr][c + 2] = v.z; T[rr][c + 3] = v.w;
    }
    __syncthreads();

    const int n  = t >> 2;
    const int ko = (t & 3) * 16;
    u16v8 h0, h1, l0, l1;
#pragma unroll
    for (int kk = 0; kk < 8; ++kk) {
        unsigned short hh, ll;
        split2(T[ko + kk][n], hh, ll);
        h0[kk] = hh; l0[kk] = ll;
    }
#pragma unroll
    for (int kk = 0; kk < 8; ++kk) {
        unsigned short hh, ll;
        split2(T[ko + 8 + kk][n], hh, ll);
        h1[kk] = hh; l1[kk] = ll;
    }
    unsigned short* Hp = &H[(size_t)(n0 + n) * 1024 + k0 + ko];
    unsigned short* Lp = &L[(size_t)(n0 + n) * 1024 + k0 + ko];
    *(u16v8*)(Hp)     = h0;
    *(u16v8*)(Hp + 8) = h1;
    *(u16v8*)(Lp)     = l0;
    *(u16v8*)(Lp + 8) = l1;
}

// ---------------------------------------------------------------------------
// bf16x3 MFMA GEMM (proven): C = A @ B + bias, epilogue modes.
// ---------------------------------------------------------------------------
__global__ __launch_bounds__(256) void gemm_bf16x3(
    const unsigned short* __restrict__ Ah, const unsigned short* __restrict__ Al,
    const unsigned short* __restrict__ Bh, const unsigned short* __restrict__ Bl,
    const float* __restrict__ bias, float* __restrict__ Cf,
    unsigned short* __restrict__ Ch, unsigned short* __restrict__ Cl, int vt)
{
    __shared__ short Ash[128][40];
    __shared__ short Asl[128][40];
    __shared__ short Bsh[128][40];
    __shared__ short Bsl[128][40];

    const int t    = threadIdx.x;
    const int bm   = blockIdx.y * 128;
    const int bn   = blockIdx.x * 128;
    const int lane = t & 63;
    const int w    = t >> 6;
    const int wr   = w >> 1;
    const int wc   = w & 1;
    const int fr   = lane & 15;
    const int fq   = lane >> 4;
    const int ks   = fq * 8;

    f32v4 zero = {0.f, 0.f, 0.f, 0.f};
    f32v4 acc[4][4];
#pragma unroll
    for (int i = 0; i < 4; ++i)
#pragma unroll
        for (int j = 0; j < 4; ++j) acc[i][j] = zero;

    const int sr = t >> 1;
    const int sc = (t & 1) * 16;
    const unsigned short* pAh = &Ah[(size_t)(bm + sr) * 1024 + sc];
    const unsigned short* pAl = &Al[(size_t)(bm + sr) * 1024 + sc];
    const unsigned short* pBh = &Bh[(size_t)(bn + sr) * 1024 + sc];
    const unsigned short* pBl = &Bl[(size_t)(bn + sr) * 1024 + sc];

    u16v8 rah0, rah1, ral0, ral1, rbh0, rbh1, rbl0, rbl1;
    auto LOAD = [&](int k0) {
        rah0 = *(const u16v8*)(pAh + k0);
        rah1 = *(const u16v8*)(pAh + k0 + 8);
        ral0 = *(const u16v8*)(pAl + k0);
        ral1 = *(const u16v8*)(pAl + k0 + 8);
        rbh0 = *(const u16v8*)(pBh + k0);
        rbh1 = *(const u16v8*)(pBh + k0 + 8);
        rbl0 = *(const u16v8*)(pBl + k0);
        rbl1 = *(const u16v8*)(pBl + k0 + 8);
    };

    LOAD(0);
    for (int k0 = 0; k0 < 1024; k0 += 32) {
        __syncthreads();
        *(u16v8*)&Ash[sr][sc]     = rah0;
        *(u16v8*)&Ash[sr][sc + 8] = rah1;
        *(u16v8*)&Asl[sr][sc]     = ral0;
        *(u16v8*)&Asl[sr][sc + 8] = ral1;
        *(u16v8*)&Bsh[sr][sc]     = rbh0;
        *(u16v8*)&Bsh[sr][sc + 8] = rbh1;
        *(u16v8*)&Bsl[sr][sc]     = rbl0;
        *(u16v8*)&Bsl[sr][sc + 8] = rbl1;
        __syncthreads();

        if (k0 + 32 < 1024) LOAD(k0 + 32);

        bf16v8 fah[4], fal[4], fbh[4], fbl[4];
#pragma unroll
        for (int i = 0; i < 4; ++i) {
            fah[i] = *(const bf16v8*)&Ash[wr * 64 + i * 16 + fr][ks];
            fal[i] = *(const bf16v8*)&Asl[wr * 64 + i * 16 + fr][ks];
            fbh[i] = *(const bf16v8*)&Bsh[wc * 64 + i * 16 + fr][ks];
            fbl[i] = *(const bf16v8*)&Bsl[wc * 64 + i * 16 + fr][ks];
        }
#pragma unroll
        for (int i = 0; i < 4; ++i)
#pragma unroll
            for (int j = 0; j < 4; ++j) {
                acc[i][j] = __builtin_amdgcn_mfma_f32_16x16x32_bf16(
                    fah[i], fbh[j], acc[i][j], 0, 0, 0);
                acc[i][j] = __builtin_amdgcn_mfma_f32_16x16x32_bf16(
                    fah[i], fbl[j], acc[i][j], 0, 0, 0);
                acc[i][j] = __builtin_amdgcn_mfma_f32_16x16x32_bf16(
                    fal[i], fbh[j], acc[i][j], 0, 0, 0);
            }
    }

#pragma unroll
    for (int j = 0; j < 4; ++j) {
        const int col = bn + wc * 64 + j * 16 + fr;
        const float bb = bias[col];
#pragma unroll
        for (int i = 0; i < 4; ++i) {
            const int row0 = bm + wr * 64 + i * 16 + fq * 4;
            const f32v4 cv = acc[i][j];
            if (vt) {
                u16v4 h4, l4;
#pragma unroll
                for (int r = 0; r < 4; ++r) {
                    unsigned short hh, ll;
                    split2(cv[r] + bb, hh, ll);
                    h4[r] = hh; l4[r] = ll;
                }
                const size_t base =
                    ((size_t)((row0 >> 10) * 16 + (col >> 6)) * 64 + (col & 63)) * 1024
                    + (row0 & 1023);
                *(u16v4*)&Ch[base] = h4;
                *(u16v4*)&Cl[base] = l4;
            } else {
#pragma unroll
                for (int r = 0; r < 4; ++r) {
                    const float v = cv[r] + bb;
                    const size_t idx = (size_t)(row0 + r) * 1024 + col;
                    if (Cf) Cf[idx] = v;
                    if (Ch) {
                        unsigned short hh, ll;
                        split2(v, hh, ll);
                        Ch[idx] = hh; Cl[idx] = ll;
                    }
                }
            }
        }
    }
}

// ---------------------------------------------------------------------------
// alpha = sigmoid(query @ Wus + bus)   [MTOT,16]
// ---------------------------------------------------------------------------
__global__ __launch_bounds__(256) void alpha_kernel(
    const float* __restrict__ X, const float* __restrict__ Wus,
    const float* __restrict__ bus, float* __restrict__ alpha)
{
    __shared__ float Ws[1024 * 16];
    const int t = threadIdx.x;
#pragma unroll
    for (int i = 0; i < 16; ++i) {
        const int idx = t + i * 256;
        *reinterpret_cast<float4*>(&Ws[idx * 4]) =
            *reinterpret_cast<const float4*>(&Wus[idx * 4]);
    }
    __syncthreads();

    const int r = t >> 4, c = t & 15;
    const size_t row = (size_t)blockIdx.x * 16 + r;
    const float* x = &X[row * 1024];
    float acc = 0.f;
    for (int kk = 0; kk < 1024; kk += 4) {
        const float4 xv = *reinterpret_cast<const float4*>(&x[kk]);
        acc = fmaf(xv.x, Ws[(kk + 0) * 16 + c], acc);
        acc = fmaf(xv.y, Ws[(kk + 1) * 16 + c], acc);
        acc = fmaf(xv.z, Ws[(kk + 2) * 16 + c], acc);
        acc = fmaf(xv.w, Ws[(kk + 3) * 16 + c], acc);
    }
    acc += bus[c];
    alpha[row * 16 + c] = 1.f / (1.f + expf(-acc));
}

// ---------------------------------------------------------------------------
// Gaussian-window parameters per (b,h,s)
// ---------------------------------------------------------------------------
__global__ __launch_bounds__(256) void posparam_kernel(
    const float* __restrict__ p, const float* __restrict__ alpha,
    const float* __restrict__ Wup, const float* __restrict__ bup,
    const float* __restrict__ Wud, const float* __restrict__ bud,
    float* __restrict__ cen, float* __restrict__ c0)
{
    __shared__ float wu[64], wd[64];
    const int t = threadIdx.x;
    if (t < 64) { wu[t] = Wup[t]; wd[t] = Wud[t]; }
    __syncthreads();

    const int tid = blockIdx.x * 256 + t;
    const int b = tid >> 14;
    const int h = (tid >> 10) & 15;
    const int s = tid & 1023;

    const float* pr = &p[((size_t)(b * 1024 + s)) * 1024 + h * 64];
    float ap = 0.f, az = 0.f;
#pragma unroll
    for (int d = 0; d < 64; d += 4) {
        const float4 pv = *reinterpret_cast<const float4*>(&pr[d]);
        const float t0 = tanhf(pv.x), t1 = tanhf(pv.y);
        const float t2 = tanhf(pv.z), t3 = tanhf(pv.w);
        ap += t0 * wu[d] + t1 * wu[d + 1] + t2 * wu[d + 2] + t3 * wu[d + 3];
        az += t0 * wd[d] + t1 * wd[d + 1] + t2 * wd[d + 2] + t3 * wd[d + 3];
    }
    ap += bup[0];
    az += bud[0];
    const float cenv = 1024.f / (1.f + expf(-ap));
    const float win  = 1024.f / (1.f + expf(-az));
    const float al   = alpha[(size_t)(b * 1024 + s) * 16 + h];
    const int oi = (b * 16 + h) * 1024 + s;
    cen[oi] = cenv;
    c0[oi]  = al * 2.f / (win * win);
}

// ---------------------------------------------------------------------------
// attn_fused v2 (swapped operands): per (z, 128-row i-tile), two passes.
// QK^T computed as T = K·Q^T -> lane holds 4 consecutive j per fixed q:
//   float4 attn stores, per-lane cen/c0/rinv, shfl-only row sums.
// PV computed as O^T = V^T·P^T with P transposed via wave-private LDS [16][64].
// LDS 48 KB -> 3 blocks/CU.
// ---------------------------------------------------------------------------
#define M0_SHIFT 8.0f
__global__ __launch_bounds__(256, 3) void attn_fused(
    const unsigned short* __restrict__ qh, const unsigned short* __restrict__ ql,
    const unsigned short* __restrict__ kh, const unsigned short* __restrict__ kl,
    const unsigned short* __restrict__ vTh, const unsigned short* __restrict__ vTl,
    const float* __restrict__ cen, const float* __restrict__ c0,
    float* __restrict__ attn,
    unsigned short* __restrict__ oh, unsigned short* __restrict__ ol)
{
    __shared__ unsigned short KH[64][64], KL[64][64];          // 16 KB
    __shared__ unsigned short VH[64][64], VL[64][64];          // 16 KB
    __shared__ unsigned short PTH[4][16][64], PTL[4][16][64];  // 16 KB (wave-private)

    // XCD-bijective mapping: all 8 i-tiles of one z land on one XCD
    const int bid   = blockIdx.x;
    const int z     = ((bid >> 6) << 3) | (bid & 7);
    const int itile = (bid >> 3) & 7;
    const int i0    = itile * 128;
    const int bq    = z >> 4;
    const int hd    = z & 15;

    const int t    = threadIdx.x;
    const int lane = t & 63;
    const int w    = t >> 6;
    const int fr   = lane & 15, fq = lane >> 4;
    const int q0w  = w * 32;                  // wave's 32-q block

    // per-lane q-row constants (q = i0 + q0w + n2*16 + fr)
    float cenq[2], c0q[2];
#pragma unroll
    for (int n2 = 0; n2 < 2; ++n2) {
        const size_t ix = (size_t)z * 1024 + i0 + q0w + n2 * 16 + fr;
        cenq[n2] = cen[ix];
        c0q[n2]  = c0[ix];
    }

    // Q fragments (B-operand): lane reads Q-row (q) 8 d-consecutive
    bf16v8 qfh_[2][2], qfl_[2][2];
#pragma unroll
    for (int n2 = 0; n2 < 2; ++n2)
#pragma unroll
        for (int kk = 0; kk < 2; ++kk) {
            const size_t qa = (size_t)(bq * 1024 + i0 + q0w + n2 * 16 + fr) * 1024
                              + hd * 64 + kk * 32 + fq * 8;
            qfh_[n2][kk] = *(const bf16v8*)&qh[qa];
            qfl_[n2][kk] = *(const bf16v8*)&ql[qa];
        }

    const f32v4 zero = {0.f, 0.f, 0.f, 0.f};
    float lsum[2] = {0.f, 0.f};

    // ---------------- PASS A: row sums ----------------
    for (int jt = 0; jt < 16; ++jt) {
        const int j0 = jt * 64;
        __syncthreads();
#pragma unroll
        for (int pp = 0; pp < 2; ++pp) {
            const int c   = t + pp * 256;
            const int row = c >> 3;
            const int seg = c & 7;
            const size_t ga = (size_t)(bq * 1024 + j0 + row) * 1024 + hd * 64 + seg * 8;
            const int sl = (seg ^ (row & 7)) * 8;
            *(u16v8*)&KH[row][sl] = *(const u16v8*)&kh[ga];
            *(u16v8*)&KL[row][sl] = *(const u16v8*)&kl[ga];
        }
        __syncthreads();

        f32v4 accT[4][2];
#pragma unroll
        for (int mi = 0; mi < 4; ++mi)
#pragma unroll
            for (int n2 = 0; n2 < 2; ++n2) accT[mi][n2] = zero;

#pragma unroll
        for (int kk = 0; kk < 2; ++kk) {
            bf16v8 kfh[4], kfl[4];
#pragma unroll
            for (int mi = 0; mi < 4; ++mi) {
                const int ra = mi * 16 + fr;
                const int sa = ((kk * 4 + fq) ^ (ra & 7)) * 8;
                kfh[mi] = *(const bf16v8*)&KH[ra][sa];
                kfl[mi] = *(const bf16v8*)&KL[ra][sa];
            }
#pragma unroll
            for (int mi = 0; mi < 4; ++mi)
#pragma unroll
                for (int n2 = 0; n2 < 2; ++n2) {
                    accT[mi][n2] = __builtin_amdgcn_mfma_f32_16x16x32_bf16(
                        kfh[mi], qfh_[n2][kk], accT[mi][n2], 0, 0, 0);
                    accT[mi][n2] = __builtin_amdgcn_mfma_f32_16x16x32_bf16(
                        kfh[mi], qfl_[n2][kk], accT[mi][n2], 0, 0, 0);
                    accT[mi][n2] = __builtin_amdgcn_mfma_f32_16x16x32_bf16(
                        kfl[mi], qfh_[n2][kk], accT[mi][n2], 0, 0, 0);
                }
        }

#pragma unroll
        for (int mi = 0; mi < 4; ++mi)
#pragma unroll
            for (int n2 = 0; n2 < 2; ++n2) {
                float al = 0.f;
#pragma unroll
                for (int r = 0; r < 4; ++r) {
                    const int j = j0 + mi * 16 + fq * 4 + r;
                    const float dd = (float)j - cenq[n2];
                    const float s  = accT[mi][n2][r] * 0.125f - c0q[n2] * dd * dd;
                    al += __expf(s - M0_SHIFT);
                }
                lsum[n2] += al;
            }
    }

    float rinv[2];
#pragma unroll
    for (int n2 = 0; n2 < 2; ++n2) {
        float v = lsum[n2];
        v += __shfl_xor(v, 16);
        v += __shfl_xor(v, 32);
        rinv[n2] = 1.f / v;
    }

    // ---------------- PASS B: attn write + PV ----------------
    f32v4 accO[4][2];
#pragma unroll
    for (int mi = 0; mi < 4; ++mi)
#pragma unroll
        for (int n2 = 0; n2 < 2; ++n2) accO[mi][n2] = zero;

    float* attnZ = attn + (size_t)z * 1024 * 1024;
    const unsigned short* vhb = vTh + (size_t)z * 64 * 1024;
    const unsigned short* vlb = vTl + (size_t)z * 64 * 1024;

    for (int jt = 0; jt < 16; ++jt) {
        const int j0 = jt * 64;
        __syncthreads();
#pragma unroll
        for (int pp = 0; pp < 2; ++pp) {
            const int c   = t + pp * 256;
            const int row = c >> 3;
            const int seg = c & 7;
            const size_t ga = (size_t)(bq * 1024 + j0 + row) * 1024 + hd * 64 + seg * 8;
            const int sl = (seg ^ (row & 7)) * 8;
            *(u16v8*)&KH[row][sl] = *(const u16v8*)&kh[ga];
            *(u16v8*)&KL[row][sl] = *(const u16v8*)&kl[ga];
            const size_t va = (size_t)row * 1024 + j0 + seg * 8;
            *(u16v8*)&VH[row][sl] = *(const u16v8*)&vhb[va];
            *(u16v8*)&VL[row][sl] = *(const u16v8*)&vlb[va];
        }
        __syncthreads();

        f32v4 accT[4][2];
#pragma unroll
        for (int mi = 0; mi < 4; ++mi)
#pragma unroll
            for (int n2 = 0; n2 < 2; ++n2) accT[mi][n2] = zero;

#pragma unroll
        for (int kk = 0; kk < 2; ++kk) {
            bf16v8 kfh[4], kfl[4];
#pragma unroll
            for (int mi = 0; mi < 4; ++mi) {
                const int ra = mi * 16 + fr;
                const int sa = ((kk * 4 + fq) ^ (ra & 7)) * 8;
                kfh[mi] = *(const bf16v8*)&KH[ra][sa];
                kfl[mi] = *(const bf16v8*)&KL[ra][sa];
            }
#pragma unroll
            for (int mi = 0; mi < 4; ++mi)
#pragma unroll
                for (int n2 = 0; n2 < 2; ++n2) {
                    accT[mi][n2] = __builtin_amdgcn_mfma_f32_16x16x32_bf16(
                        kfh[mi], qfh_[n2][kk], accT[mi][n2], 0, 0, 0);
                    accT[mi][n2] = __builtin_amdgcn_mfma_f32_16x16x32_bf16(
                        kfh[mi], qfl_[n2][kk], accT[mi][n2], 0, 0, 0);
                    accT[mi][n2] = __builtin_amdgcn_mfma_f32_16x16x32_bf16(
                        kfl[mi], qfh_[n2][kk], accT[mi][n2], 0, 0, 0);
                }
        }

        // per n2-block: P epilogue (attn float4 store + P^T LDS) then PV
#pragma unroll
        for (int n2 = 0; n2 < 2; ++n2) {
            const float cv = cenq[n2], cc = c0q[n2], ri = rinv[n2];
            const size_t arow = (size_t)(i0 + q0w + n2 * 16 + fr) * 1024 + j0;
#pragma unroll
            for (int mi = 0; mi < 4; ++mi) {
                float4 pv4;
                u16v4 h4, l4;
#pragma unroll
                for (int r = 0; r < 4; ++r) {
                    const int j = j0 + mi * 16 + fq * 4 + r;
                    const float dd = (float)j - cv;
                    const float s  = accT[mi][n2][r] * 0.125f - cc * dd * dd;
                    const float p  = __expf(s - M0_SHIFT) * ri;
                    ((float*)&pv4)[r] = p;
                    unsigned short hh, ll;
                    split2(p, hh, ll);
                    h4[r] = hh; l4[r] = ll;
                }
                *(float4*)&attnZ[arow + mi * 16 + fq * 4] = pv4;
                const int slot = (mi * 2 + (fq >> 1)) ^ (fr & 7);
                const int off  = slot * 8 + (fq & 1) * 4;
                *(u16v4*)&PTH[w][fr][off] = h4;
                *(u16v4*)&PTL[w][fr][off] = l4;
            }
            // PV: O^T[d][q] += V^T-frag · P^T-frag  (wave-private P^T, no barrier)
#pragma unroll
            for (int kk = 0; kk < 2; ++kk) {
                const int ps = ((kk * 4 + fq) ^ (fr & 7)) * 8;
                const bf16v8 pfh = *(const bf16v8*)&PTH[w][fr][ps];
                const bf16v8 pfl = *(const bf16v8*)&PTL[w][fr][ps];
#pragma unroll
                for (int mi = 0; mi < 4; ++mi) {
                    const int rv = mi * 16 + fr;
                    const int sv = ((kk * 4 + fq) ^ (rv & 7)) * 8;
                    const bf16v8 vfh = *(const bf16v8*)&VH[rv][sv];
                    const bf16v8 vfl = *(const bf16v8*)&VL[rv][sv];
                    accO[mi][n2] = __builtin_amdgcn_mfma_f32_16x16x32_bf16(
                        vfh, pfh, accO[mi][n2], 0, 0, 0);
                    accO[mi][n2] = __builtin_amdgcn_mfma_f32_16x16x32_bf16(
                        vfh, pfl, accO[mi][n2], 0, 0, 0);
                    accO[mi][n2] = __builtin_amdgcn_mfma_f32_16x16x32_bf16(
                        vfl, pfh, accO[mi][n2], 0, 0, 0);
                }
            }
        }
    }

    // epilogue: O^T[d][q] -> o row-major [4096][1024]; 4 consecutive d per lane
#pragma unroll
    for (int n2 = 0; n2 < 2; ++n2) {
        const size_t orow = (size_t)(bq * 1024 + i0 + q0w + n2 * 16 + fr) * 1024 + hd * 64;
#pragma unroll
        for (int mi = 0; mi < 4; ++mi) {
            const f32v4 cv = accO[mi][n2];
            u16v4 h4, l4;
#pragma unroll
            for (int r = 0; r < 4; ++r) {
                unsigned short hv, lv;
                split2(cv[r], hv, lv);
                h4[r] = hv; l4[r] = lv;
            }
            const size_t idx = orow + mi * 16 + fq * 4;
            *(u16v4*)&oh[idx] = h4;
            *(u16v4*)&ol[idx] = l4;
        }
    }
}

// ---------------------------------------------------------------------------
extern "C" void kernel_launch(void* const* d_in, const int* in_sizes, int n_in,
                              void* d_out, int out_size, void* d_ws, size_t ws_size,
                              hipStream_t stream)
{
    const float* query = (const float*)d_in[0];
    const float* key_  = (const float*)d_in[1];
    const float* value = (const float*)d_in[2];
    const float* Wq  = (const float*)d_in[3];
    const float* bq  = (const float*)d_in[4];
    const float* Wk  = (const float*)d_in[5];
    const float* bk  = (const float*)d_in[6];
    const float* Wv  = (const float*)d_in[7];
    const float* bv  = (const float*)d_in[8];
    const float* Wp  = (const float*)d_in[9];
    const float* bp  = (const float*)d_in[10];
    const float* Wup = (const float*)d_in[11];
    const float* bup = (const float*)d_in[12];
    const float* Wud = (const float*)d_in[13];
    const float* bud = (const float*)d_in[14];
    const float* Wus = (const float*)d_in[15];
    const float* bus = (const float*)d_in[16];
    const float* Wo  = (const float*)d_in[17];
    const float* bo  = (const float*)d_in[18];

    float* x_out = (float*)d_out;                         // [4096,1024]
    float* attn  = x_out + (size_t)MTOT * HIDN;           // [64,1024,1024]

    // ---- workspace layout (bytes)
    char* wsb = (char*)d_ws;
    unsigned short* qh  = (unsigned short*)(wsb);                  // 8 MB
    unsigned short* ql  = (unsigned short*)(wsb + (8u  << 20));
    unsigned short* kh  = (unsigned short*)(wsb + (16u << 20));
    unsigned short* kl  = (unsigned short*)(wsb + (24u << 20));
    unsigned short* vTh = (unsigned short*)(wsb + (32u << 20));
    unsigned short* vTl = (unsigned short*)(wsb + (40u << 20));
    float* p_ws  = (float*)(wsb + (48u << 20));                    // 16 MB
    unsigned short* oh = (unsigned short*)(wsb + (48u << 20));     // overlays p
    unsigned short* ol = (unsigned short*)(wsb + (56u << 20));
    float* alpha_ws = (float*)(wsb + (64u << 20));                 // 256 KB
    float* cen_ws   = (float*)(wsb + (64u << 20) + (256u << 10));
    float* c0_ws    = (float*)(wsb + (64u << 20) + (512u << 10));
    // stage-1 split scratch lives in the (not-yet-written) attn region
    unsigned short* ah = (unsigned short*)attn;                    // 8 MB
    unsigned short* al = ah + (size_t)MTOT * HIDN;                 // 8 MB
    unsigned short* wh = al + (size_t)MTOT * HIDN;                 // 2 MB
    unsigned short* wl = wh + (size_t)HIDN * HIDN;                 // 2 MB
    // Wo split reuses qh/ql space after attn_fused
    unsigned short* w2h = qh;
    unsigned short* w2l = ql;

    const dim3 blk(256);
    const dim3 gsplit_a(MTOT * HIDN / 8 / 256);
    const dim3 gsplit_w(16, 16);
    const dim3 ggemm(HIDN / 128, MTOT / 128);

    // q = query @ Wq + bq -> qh/ql (bf16 only)
    split_w<<<gsplit_w, blk, 0, stream>>>(Wq, wh, wl);
    split_a<<<gsplit_a, blk, 0, stream>>>(query, ah, al);
    gemm_bf16x3<<<ggemm, blk, 0, stream>>>(ah, al, wh, wl, bq, nullptr, qh, ql, 0);
    // k -> kh/kl
    split_w<<<gsplit_w, blk, 0, stream>>>(Wk, wh, wl);
    split_a<<<gsplit_a, blk, 0, stream>>>(key_, ah, al);
    gemm_bf16x3<<<ggemm, blk, 0, stream>>>(ah, al, wh, wl, bk, nullptr, kh, kl, 0);
    // v -> vTh/vTl (per-head transposed)
    split_w<<<gsplit_w, blk, 0, stream>>>(Wv, wh, wl);
    split_a<<<gsplit_a, blk, 0, stream>>>(value, ah, al);
    gemm_bf16x3<<<ggemm, blk, 0, stream>>>(ah, al, wh, wl, bv, nullptr, vTh, vTl, 1);
    // p = q @ Wp + bp -> p_ws (f32); A is already-split qh/ql
    split_w<<<gsplit_w, blk, 0, stream>>>(Wp, wh, wl);
    gemm_bf16x3<<<ggemm, blk, 0, stream>>>(qh, ql, wh, wl, bp, p_ws, nullptr, nullptr, 0);
    // alpha + window params
    alpha_kernel<<<dim3(MTOT / 16), blk, 0, stream>>>(query, Wus, bus, alpha_ws);
    posparam_kernel<<<dim3((BATCH * NHEAD * S_LEN) / 256), blk, 0, stream>>>(
        p_ws, alpha_ws, Wup, bup, Wud, bud, cen_ws, c0_ws);
    // fused scores + softmax + attn-write + PV
    attn_fused<<<dim3(512), blk, 0, stream>>>(
        qh, ql, kh, kl, vTh, vTl, cen_ws, c0_ws, attn, oh, ol);
    // x = o @ Wo + bo
    split_w<<<gsplit_w, blk, 0, stream>>>(Wo, w2h, w2l);
    gemm_bf16x3<<<ggemm, blk, 0, stream>>>(oh, ol, w2h, w2l, bo, x_out,
                                           nullptr, nullptr, 0);
}

// Round 6
// 455.470 us; speedup vs baseline: 1.0015x; 1.0015x over previous
//
#include <hip/hip_runtime.h>
#include <hip/hip_bf16.h>
#include <math.h>

#define S_LEN 1024
#define HIDN  1024
#define NHEAD 16
#define HDIM  64
#define BATCH 4
#define MTOT  (BATCH * S_LEN)   // 4096

typedef __attribute__((ext_vector_type(8))) short          bf16v8;
typedef __attribute__((ext_vector_type(8))) unsigned short u16v8;
typedef __attribute__((ext_vector_type(4))) unsigned short u16v4;
typedef __attribute__((ext_vector_type(4))) float          f32v4;

// ---------------------------------------------------------------------------
// bf16 hi/lo split helpers (RNE)
// ---------------------------------------------------------------------------
__device__ __forceinline__ unsigned short f2bf_rne(float x) {
    unsigned int u = __float_as_uint(x);
    unsigned int r = (u + 0x7fffu + ((u >> 16) & 1u)) >> 16;
    return (unsigned short)r;
}
__device__ __forceinline__ float bf2f(unsigned short h) {
    return __uint_as_float(((unsigned int)h) << 16);
}
__device__ __forceinline__ void split2(float x, unsigned short& h, unsigned short& l) {
    h = f2bf_rne(x);
    l = f2bf_rne(x - bf2f(h));
}

// ---------------------------------------------------------------------------
// split_a: row-major f32 [M][1024] -> Ah, Al bf16 (same layout).
// ---------------------------------------------------------------------------
__global__ __launch_bounds__(256) void split_a(
    const float* __restrict__ X, unsigned short* __restrict__ H,
    unsigned short* __restrict__ L)
{
    const int i = blockIdx.x * 256 + threadIdx.x;
    const float4 x0 = ((const float4*)X)[2 * i];
    const float4 x1 = ((const float4*)X)[2 * i + 1];
    float xs[8] = {x0.x, x0.y, x0.z, x0.w, x1.x, x1.y, x1.z, x1.w};
    u16v8 h, l;
#pragma unroll
    for (int j = 0; j < 8; ++j) {
        unsigned short hh, ll;
        split2(xs[j], hh, ll);
        h[j] = hh; l[j] = ll;
    }
    ((u16v8*)H)[i] = h;
    ((u16v8*)L)[i] = l;
}

// ---------------------------------------------------------------------------
// split_w: W f32 [K=1024][N=1024] -> transposed Ht, Lt bf16 [N][K] (k-contig).
// ---------------------------------------------------------------------------
__global__ __launch_bounds__(256) void split_w(
    const float* __restrict__ W, unsigned short* __restrict__ H,
    unsigned short* __restrict__ L)
{
    __shared__ float T[64][65];
    const int t  = threadIdx.x;
    const int k0 = blockIdx.y * 64;
    const int n0 = blockIdx.x * 64;

    const int r = t >> 4;
    const int c = (t & 15) * 4;
#pragma unroll
    for (int i = 0; i < 4; ++i) {
        const int rr = r + i * 16;
        const float4 v = *(const float4*)&W[(size_t)(k0 + rr) * 1024 + n0 + c];
        T[rr][c + 0] = v.x; T[rr][c + 1] = v.y;
        T[rr][c + 2] = v.z; T[rr][c + 3] = v.w;
    }
    __syncthreads();

    const int n  = t >> 2;
    const int ko = (t & 3) * 16;
    u16v8 h0, h1, l0, l1;
#pragma unroll
    for (int kk = 0; kk < 8; ++kk) {
        unsigned short hh, ll;
        split2(T[ko + kk][n], hh, ll);
        h0[kk] = hh; l0[kk] = ll;
    }
#pragma unroll
    for (int kk = 0; kk < 8; ++kk) {
        unsigned short hh, ll;
        split2(T[ko + 8 + kk][n], hh, ll);
        h1[kk] = hh; l1[kk] = ll;
    }
    unsigned short* Hp = &H[(size_t)(n0 + n) * 1024 + k0 + ko];
    unsigned short* Lp = &L[(size_t)(n0 + n) * 1024 + k0 + ko];
    *(u16v8*)(Hp)     = h0;
    *(u16v8*)(Hp + 8) = h1;
    *(u16v8*)(Lp)     = l0;
    *(u16v8*)(Lp + 8) = l1;
}

// ---------------------------------------------------------------------------
// bf16x3 MFMA GEMM: C = A(hi/lo bf16 [M][1024]) @ B(hi/lo [n][k]) + bias.
// BM=128, BN=64, BK=32, 256 threads (4 waves 2x2), wave 64x32 out.
// Grid (16,32) = 512 blocks -> 2 blocks/CU (was 1 at BN=128).
// ---------------------------------------------------------------------------
__global__ __launch_bounds__(256) void gemm_bf16x3(
    const unsigned short* __restrict__ Ah, const unsigned short* __restrict__ Al,
    const unsigned short* __restrict__ Bh, const unsigned short* __restrict__ Bl,
    const float* __restrict__ bias, float* __restrict__ Cf,
    unsigned short* __restrict__ Ch, unsigned short* __restrict__ Cl, int vt)
{
    __shared__ short Ash[128][40];
    __shared__ short Asl[128][40];
    __shared__ short Bsh[64][40];
    __shared__ short Bsl[64][40];

    const int t    = threadIdx.x;
    const int bm   = blockIdx.y * 128;
    const int bn   = blockIdx.x * 64;
    const int lane = t & 63;
    const int w    = t >> 6;
    const int wr   = w >> 1;
    const int wc   = w & 1;
    const int fr   = lane & 15;
    const int fq   = lane >> 4;
    const int ks   = fq * 8;

    f32v4 zero = {0.f, 0.f, 0.f, 0.f};
    f32v4 acc[4][2];
#pragma unroll
    for (int i = 0; i < 4; ++i)
#pragma unroll
        for (int j = 0; j < 2; ++j) acc[i][j] = zero;

    // staging: thread -> row t>>2 (0..63), 8-short chunk (t&3)*8
    const int sr = t >> 2;
    const int sc = (t & 3) * 8;
    const unsigned short* pAh = &Ah[(size_t)(bm + sr) * 1024 + sc];
    const unsigned short* pAl = &Al[(size_t)(bm + sr) * 1024 + sc];
    const unsigned short* pBh = &Bh[(size_t)(bn + sr) * 1024 + sc];
    const unsigned short* pBl = &Bl[(size_t)(bn + sr) * 1024 + sc];
    const size_t arow2 = (size_t)64 * 1024;

    u16v8 rah0, rah1, ral0, ral1, rbh0, rbl0;
    auto LOAD = [&](int k0) {
        rah0 = *(const u16v8*)(pAh + k0);
        rah1 = *(const u16v8*)(pAh + arow2 + k0);
        ral0 = *(const u16v8*)(pAl + k0);
        ral1 = *(const u16v8*)(pAl + arow2 + k0);
        rbh0 = *(const u16v8*)(pBh + k0);
        rbl0 = *(const u16v8*)(pBl + k0);
    };

    LOAD(0);
    for (int k0 = 0; k0 < 1024; k0 += 32) {
        __syncthreads();
        *(u16v8*)&Ash[sr][sc]      = rah0;
        *(u16v8*)&Ash[sr + 64][sc] = rah1;
        *(u16v8*)&Asl[sr][sc]      = ral0;
        *(u16v8*)&Asl[sr + 64][sc] = ral1;
        *(u16v8*)&Bsh[sr][sc]      = rbh0;
        *(u16v8*)&Bsl[sr][sc]      = rbl0;
        __syncthreads();

        if (k0 + 32 < 1024) LOAD(k0 + 32);

        bf16v8 fah[4], fal[4], fbh[2], fbl[2];
#pragma unroll
        for (int i = 0; i < 4; ++i) {
            fah[i] = *(const bf16v8*)&Ash[wr * 64 + i * 16 + fr][ks];
            fal[i] = *(const bf16v8*)&Asl[wr * 64 + i * 16 + fr][ks];
        }
#pragma unroll
        for (int j = 0; j < 2; ++j) {
            fbh[j] = *(const bf16v8*)&Bsh[wc * 32 + j * 16 + fr][ks];
            fbl[j] = *(const bf16v8*)&Bsl[wc * 32 + j * 16 + fr][ks];
        }
#pragma unroll
        for (int i = 0; i < 4; ++i)
#pragma unroll
            for (int j = 0; j < 2; ++j) {
                acc[i][j] = __builtin_amdgcn_mfma_f32_16x16x32_bf16(
                    fah[i], fbh[j], acc[i][j], 0, 0, 0);
                acc[i][j] = __builtin_amdgcn_mfma_f32_16x16x32_bf16(
                    fah[i], fbl[j], acc[i][j], 0, 0, 0);
                acc[i][j] = __builtin_amdgcn_mfma_f32_16x16x32_bf16(
                    fal[i], fbh[j], acc[i][j], 0, 0, 0);
            }
    }

#pragma unroll
    for (int j = 0; j < 2; ++j) {
        const int col = bn + wc * 32 + j * 16 + fr;
        const float bb = bias[col];
#pragma unroll
        for (int i = 0; i < 4; ++i) {
            const int row0 = bm + wr * 64 + i * 16 + fq * 4;
            const f32v4 cv = acc[i][j];
            if (vt) {
                u16v4 h4, l4;
#pragma unroll
                for (int r = 0; r < 4; ++r) {
                    unsigned short hh, ll;
                    split2(cv[r] + bb, hh, ll);
                    h4[r] = hh; l4[r] = ll;
                }
                const size_t base =
                    ((size_t)((row0 >> 10) * 16 + (col >> 6)) * 64 + (col & 63)) * 1024
                    + (row0 & 1023);
                *(u16v4*)&Ch[base] = h4;
                *(u16v4*)&Cl[base] = l4;
            } else {
#pragma unroll
                for (int r = 0; r < 4; ++r) {
                    const float v = cv[r] + bb;
                    const size_t idx = (size_t)(row0 + r) * 1024 + col;
                    if (Cf) Cf[idx] = v;
                    if (Ch) {
                        unsigned short hh, ll;
                        split2(v, hh, ll);
                        Ch[idx] = hh; Cl[idx] = ll;
                    }
                }
            }
        }
    }
}

// ---------------------------------------------------------------------------
// alpha = sigmoid(query @ Wus + bus)   [MTOT,16]
// ---------------------------------------------------------------------------
__global__ __launch_bounds__(256) void alpha_kernel(
    const float* __restrict__ X, const float* __restrict__ Wus,
    const float* __restrict__ bus, float* __restrict__ alpha)
{
    __shared__ float Ws[1024 * 16];
    const int t = threadIdx.x;
#pragma unroll
    for (int i = 0; i < 16; ++i) {
        const int idx = t + i * 256;
        *reinterpret_cast<float4*>(&Ws[idx * 4]) =
            *reinterpret_cast<const float4*>(&Wus[idx * 4]);
    }
    __syncthreads();

    const int r = t >> 4, c = t & 15;
    const size_t row = (size_t)blockIdx.x * 16 + r;
    const float* x = &X[row * 1024];
    float acc = 0.f;
    for (int kk = 0; kk < 1024; kk += 4) {
        const float4 xv = *reinterpret_cast<const float4*>(&x[kk]);
        acc = fmaf(xv.x, Ws[(kk + 0) * 16 + c], acc);
        acc = fmaf(xv.y, Ws[(kk + 1) * 16 + c], acc);
        acc = fmaf(xv.z, Ws[(kk + 2) * 16 + c], acc);
        acc = fmaf(xv.w, Ws[(kk + 3) * 16 + c], acc);
    }
    acc += bus[c];
    alpha[row * 16 + c] = 1.f / (1.f + expf(-acc));
}

// ---------------------------------------------------------------------------
// Gaussian-window parameters per (b,h,s)
// ---------------------------------------------------------------------------
__global__ __launch_bounds__(256) void posparam_kernel(
    const float* __restrict__ p, const float* __restrict__ alpha,
    const float* __restrict__ Wup, const float* __restrict__ bup,
    const float* __restrict__ Wud, const float* __restrict__ bud,
    float* __restrict__ cen, float* __restrict__ c0)
{
    __shared__ float wu[64], wd[64];
    const int t = threadIdx.x;
    if (t < 64) { wu[t] = Wup[t]; wd[t] = Wud[t]; }
    __syncthreads();

    const int tid = blockIdx.x * 256 + t;
    const int b = tid >> 14;
    const int h = (tid >> 10) & 15;
    const int s = tid & 1023;

    const float* pr = &p[((size_t)(b * 1024 + s)) * 1024 + h * 64];
    float ap = 0.f, az = 0.f;
#pragma unroll
    for (int d = 0; d < 64; d += 4) {
        const float4 pv = *reinterpret_cast<const float4*>(&pr[d]);
        const float t0 = tanhf(pv.x), t1 = tanhf(pv.y);
        const float t2 = tanhf(pv.z), t3 = tanhf(pv.w);
        ap += t0 * wu[d] + t1 * wu[d + 1] + t2 * wu[d + 2] + t3 * wu[d + 3];
        az += t0 * wd[d] + t1 * wd[d + 1] + t2 * wd[d + 2] + t3 * wd[d + 3];
    }
    ap += bup[0];
    az += bud[0];
    const float cenv = 1024.f / (1.f + expf(-ap));
    const float win  = 1024.f / (1.f + expf(-az));
    const float al   = alpha[(size_t)(b * 1024 + s) * 16 + h];
    const int oi = (b * 16 + h) * 1024 + s;
    cen[oi] = cenv;
    c0[oi]  = al * 2.f / (win * win);
}

// ---------------------------------------------------------------------------
// attn_fused v3: round-4 structure with 64-row i-tiles.
// Grid 1024 blocks (4/CU available), LDS ~49 KB -> 3 blocks/CU.
//  Pass A: recompute S (bf16x3 MFMA, Q in regs), l = sum exp(s-8) -> RINV.
//  Pass B: recompute S, write attn = exp(s-8)*rinv (f32 output), scatter P
//          bf16 hi/lo into swizzled LDS, PV MFMA -> oh/ol.
// ---------------------------------------------------------------------------
#define M0_SHIFT 8.0f
__global__ __launch_bounds__(256, 3) void attn_fused(
    const unsigned short* __restrict__ qh, const unsigned short* __restrict__ ql,
    const unsigned short* __restrict__ kh, const unsigned short* __restrict__ kl,
    const unsigned short* __restrict__ vTh, const unsigned short* __restrict__ vTl,
    const float* __restrict__ cen, const float* __restrict__ c0,
    float* __restrict__ attn,
    unsigned short* __restrict__ oh, unsigned short* __restrict__ ol)
{
    __shared__ unsigned short KH[64][64], KL[64][64];   // 16 KB
    __shared__ unsigned short VH[64][64], VL[64][64];   // 16 KB
    __shared__ unsigned short PH[64][64], PL[64][64];   // 16 KB
    __shared__ float CEN[64], C0S[64];
    __shared__ float LSUM[2][64];
    __shared__ float RINV[64];

    // XCD mapping: all 16 i-tiles of one z land on one XCD (bid&7 = XCD)
    const int bid   = blockIdx.x;
    const int z     = ((bid >> 7) << 3) | (bid & 7);
    const int itile = (bid >> 3) & 15;
    const int i0    = itile * 64;
    const int bq    = z >> 4;
    const int hd    = z & 15;

    const int t    = threadIdx.x;
    const int lane = t & 63;
    const int w    = t >> 6;
    const int wr   = w >> 1, wc = w & 1;
    const int fr   = lane & 15, fq = lane >> 4;

    if (t < 64) {
        CEN[t] = cen[(size_t)z * 1024 + i0 + t];
        C0S[t] = c0[(size_t)z * 1024 + i0 + t];
    }

    // Q fragments in registers (A-frag: row = fr, k = kk*32 + fq*8)
    bf16v8 qfh_[2][2], qfl_[2][2];
#pragma unroll
    for (int i = 0; i < 2; ++i)
#pragma unroll
        for (int kk = 0; kk < 2; ++kk) {
            const size_t qa = (size_t)(bq * 1024 + i0 + wr * 32 + i * 16 + fr) * 1024
                              + hd * 64 + kk * 32 + fq * 8;
            qfh_[i][kk] = *(const bf16v8*)&qh[qa];
            qfl_[i][kk] = *(const bf16v8*)&ql[qa];
        }

    float lsum[2][4];
#pragma unroll
    for (int i = 0; i < 2; ++i)
#pragma unroll
        for (int r = 0; r < 4; ++r) lsum[i][r] = 0.f;

    const f32v4 zero = {0.f, 0.f, 0.f, 0.f};

    // ---------------- PASS A: row sums ----------------
    for (int jt = 0; jt < 16; ++jt) {
        const int j0 = jt * 64;
        __syncthreads();
#pragma unroll
        for (int pp = 0; pp < 2; ++pp) {
            const int c   = t + pp * 256;
            const int row = c >> 3;
            const int seg = c & 7;
            const size_t ga = (size_t)(bq * 1024 + j0 + row) * 1024 + hd * 64 + seg * 8;
            const int sl = (seg ^ (row & 7)) * 8;
            *(u16v8*)&KH[row][sl] = *(const u16v8*)&kh[ga];
            *(u16v8*)&KL[row][sl] = *(const u16v8*)&kl[ga];
        }
        __syncthreads();

        f32v4 acc[2][2];
#pragma unroll
        for (int i = 0; i < 2; ++i)
#pragma unroll
            for (int j2 = 0; j2 < 2; ++j2) acc[i][j2] = zero;

#pragma unroll
        for (int kk = 0; kk < 2; ++kk) {
            bf16v8 fbh[2], fbl[2];
#pragma unroll
            for (int j2 = 0; j2 < 2; ++j2) {
                const int rb = wc * 32 + j2 * 16 + fr;
                const int sb = ((kk * 4 + fq) ^ (rb & 7)) * 8;
                fbh[j2] = *(const bf16v8*)&KH[rb][sb];
                fbl[j2] = *(const bf16v8*)&KL[rb][sb];
            }
#pragma unroll
            for (int i = 0; i < 2; ++i)
#pragma unroll
                for (int j2 = 0; j2 < 2; ++j2) {
                    acc[i][j2] = __builtin_amdgcn_mfma_f32_16x16x32_bf16(
                        qfh_[i][kk], fbh[j2], acc[i][j2], 0, 0, 0);
                    acc[i][j2] = __builtin_amdgcn_mfma_f32_16x16x32_bf16(
                        qfh_[i][kk], fbl[j2], acc[i][j2], 0, 0, 0);
                    acc[i][j2] = __builtin_amdgcn_mfma_f32_16x16x32_bf16(
                        qfl_[i][kk], fbh[j2], acc[i][j2], 0, 0, 0);
                }
        }

#pragma unroll
        for (int i = 0; i < 2; ++i)
#pragma unroll
            for (int r = 0; r < 4; ++r) {
                const int row = wr * 32 + i * 16 + fq * 4 + r;
                const float cv = CEN[row], cc = C0S[row];
                float al = 0.f;
#pragma unroll
                for (int j2 = 0; j2 < 2; ++j2) {
                    const int col = wc * 32 + j2 * 16 + fr;
                    const float dd = (float)(j0 + col) - cv;
                    const float s  = acc[i][j2][r] * 0.125f - cc * dd * dd;
                    al += __expf(s - M0_SHIFT);
                }
                lsum[i][r] += al;
            }
    }

    // reduce over fr lanes, store per-wc partials
#pragma unroll
    for (int i = 0; i < 2; ++i)
#pragma unroll
        for (int r = 0; r < 4; ++r) {
            float v = lsum[i][r];
            v += __shfl_xor(v, 1);
            v += __shfl_xor(v, 2);
            v += __shfl_xor(v, 4);
            v += __shfl_xor(v, 8);
            if (fr == 0) LSUM[wc][wr * 32 + i * 16 + fq * 4 + r] = v;
        }
    __syncthreads();
    if (t < 64) RINV[t] = 1.f / (LSUM[0][t] + LSUM[1][t]);

    // ---------------- PASS B: attn write + PV ----------------
    f32v4 acco[2][2];
#pragma unroll
    for (int i = 0; i < 2; ++i)
#pragma unroll
        for (int j = 0; j < 2; ++j) acco[i][j] = zero;

    float* attnZ = attn + (size_t)z * 1024 * 1024;
    const unsigned short* vhb = vTh + (size_t)z * 64 * 1024;
    const unsigned short* vlb = vTl + (size_t)z * 64 * 1024;

    for (int jt = 0; jt < 16; ++jt) {
        const int j0 = jt * 64;
        __syncthreads();   // prev PV reads done; RINV visible on first iter
#pragma unroll
        for (int pp = 0; pp < 2; ++pp) {
            const int c   = t + pp * 256;
            const int row = c >> 3;
            const int seg = c & 7;
            const size_t ga = (size_t)(bq * 1024 + j0 + row) * 1024 + hd * 64 + seg * 8;
            const int sl = (seg ^ (row & 7)) * 8;
            *(u16v8*)&KH[row][sl] = *(const u16v8*)&kh[ga];
            *(u16v8*)&KL[row][sl] = *(const u16v8*)&kl[ga];
            const size_t va = (size_t)row * 1024 + j0 + seg * 8;
            *(u16v8*)&VH[row][sl] = *(const u16v8*)&vhb[va];
            *(u16v8*)&VL[row][sl] = *(const u16v8*)&vlb[va];
        }
        __syncthreads();

        f32v4 acc[2][2];
#pragma unroll
        for (int i = 0; i < 2; ++i)
#pragma unroll
            for (int j2 = 0; j2 < 2; ++j2) acc[i][j2] = zero;

#pragma unroll
        for (int kk = 0; kk < 2; ++kk) {
            bf16v8 fbh[2], fbl[2];
#pragma unroll
            for (int j2 = 0; j2 < 2; ++j2) {
                const int rb = wc * 32 + j2 * 16 + fr;
                const int sb = ((kk * 4 + fq) ^ (rb & 7)) * 8;
                fbh[j2] = *(const bf16v8*)&KH[rb][sb];
                fbl[j2] = *(const bf16v8*)&KL[rb][sb];
            }
#pragma unroll
            for (int i = 0; i < 2; ++i)
#pragma unroll
                for (int j2 = 0; j2 < 2; ++j2) {
                    acc[i][j2] = __builtin_amdgcn_mfma_f32_16x16x32_bf16(
                        qfh_[i][kk], fbh[j2], acc[i][j2], 0, 0, 0);
                    acc[i][j2] = __builtin_amdgcn_mfma_f32_16x16x32_bf16(
                        qfh_[i][kk], fbl[j2], acc[i][j2], 0, 0, 0);
                    acc[i][j2] = __builtin_amdgcn_mfma_f32_16x16x32_bf16(
                        qfl_[i][kk], fbh[j2], acc[i][j2], 0, 0, 0);
                }
        }

        // P = exp(s-8)*rinv: write attn f32 + scatter bf16 hi/lo to LDS
#pragma unroll
        for (int i = 0; i < 2; ++i)
#pragma unroll
            for (int r = 0; r < 4; ++r) {
                const int row = wr * 32 + i * 16 + fq * 4 + r;
                const float cv = CEN[row], cc = C0S[row], ri = RINV[row];
#pragma unroll
                for (int j2 = 0; j2 < 2; ++j2) {
                    const int col = wc * 32 + j2 * 16 + fr;
                    const float dd = (float)(j0 + col) - cv;
                    const float s  = acc[i][j2][r] * 0.125f - cc * dd * dd;
                    const float p  = __expf(s - M0_SHIFT) * ri;
                    attnZ[(size_t)(i0 + row) * 1024 + j0 + col] = p;
                    unsigned short hv, lv;
                    split2(p, hv, lv);
                    const int slot = ((col >> 3) ^ (row & 7)) * 8 + (col & 7);
                    PH[row][slot] = hv;
                    PL[row][slot] = lv;
                }
            }
        __syncthreads();

        // PV MFMA: out[64 q][64 d] += P[64][64] @ Vt[64 d][64 j]^T
#pragma unroll
        for (int kk = 0; kk < 2; ++kk) {
            bf16v8 pah[2], pal[2], fbh[2], fbl[2];
#pragma unroll
            for (int iq = 0; iq < 2; ++iq) {
                const int rp = wr * 32 + iq * 16 + fr;
                const int sp = ((kk * 4 + fq) ^ (rp & 7)) * 8;
                pah[iq] = *(const bf16v8*)&PH[rp][sp];
                pal[iq] = *(const bf16v8*)&PL[rp][sp];
            }
#pragma unroll
            for (int jd = 0; jd < 2; ++jd) {
                const int rb = wc * 32 + jd * 16 + fr;
                const int sb = ((kk * 4 + fq) ^ (rb & 7)) * 8;
                fbh[jd] = *(const bf16v8*)&VH[rb][sb];
                fbl[jd] = *(const bf16v8*)&VL[rb][sb];
            }
#pragma unroll
            for (int iq = 0; iq < 2; ++iq)
#pragma unroll
                for (int jd = 0; jd < 2; ++jd) {
                    acco[iq][jd] = __builtin_amdgcn_mfma_f32_16x16x32_bf16(
                        pah[iq], fbh[jd], acco[iq][jd], 0, 0, 0);
                    acco[iq][jd] = __builtin_amdgcn_mfma_f32_16x16x32_bf16(
                        pah[iq], fbl[jd], acco[iq][jd], 0, 0, 0);
                    acco[iq][jd] = __builtin_amdgcn_mfma_f32_16x16x32_bf16(
                        pal[iq], fbh[jd], acco[iq][jd], 0, 0, 0);
                }
        }
    }

    // epilogue: o row-major [4096][1024], col = h*64 + d, bf16 hi/lo
#pragma unroll
    for (int jd = 0; jd < 2; ++jd) {
        const int dcol = wc * 32 + jd * 16 + fr;
#pragma unroll
        for (int iq = 0; iq < 2; ++iq) {
            const int row0 = i0 + wr * 32 + iq * 16 + fq * 4;
            const f32v4 cv = acco[iq][jd];
#pragma unroll
            for (int r = 0; r < 4; ++r) {
                unsigned short hv, lv;
                split2(cv[r], hv, lv);
                const size_t idx = (size_t)(bq * 1024 + row0 + r) * 1024 + hd * 64 + dcol;
                oh[idx] = hv;
                ol[idx] = lv;
            }
        }
    }
}

// ---------------------------------------------------------------------------
extern "C" void kernel_launch(void* const* d_in, const int* in_sizes, int n_in,
                              void* d_out, int out_size, void* d_ws, size_t ws_size,
                              hipStream_t stream)
{
    const float* query = (const float*)d_in[0];
    const float* key_  = (const float*)d_in[1];
    const float* value = (const float*)d_in[2];
    const float* Wq  = (const float*)d_in[3];
    const float* bq  = (const float*)d_in[4];
    const float* Wk  = (const float*)d_in[5];
    const float* bk  = (const float*)d_in[6];
    const float* Wv  = (const float*)d_in[7];
    const float* bv  = (const float*)d_in[8];
    const float* Wp  = (const float*)d_in[9];
    const float* bp  = (const float*)d_in[10];
    const float* Wup = (const float*)d_in[11];
    const float* bup = (const float*)d_in[12];
    const float* Wud = (const float*)d_in[13];
    const float* bud = (const float*)d_in[14];
    const float* Wus = (const float*)d_in[15];
    const float* bus = (const float*)d_in[16];
    const float* Wo  = (const float*)d_in[17];
    const float* bo  = (const float*)d_in[18];

    float* x_out = (float*)d_out;                         // [4096,1024]
    float* attn  = x_out + (size_t)MTOT * HIDN;           // [64,1024,1024]

    // ---- workspace layout (bytes)
    char* wsb = (char*)d_ws;
    unsigned short* qh  = (unsigned short*)(wsb);                  // 8 MB
    unsigned short* ql  = (unsigned short*)(wsb + (8u  << 20));
    unsigned short* kh  = (unsigned short*)(wsb + (16u << 20));
    unsigned short* kl  = (unsigned short*)(wsb + (24u << 20));
    unsigned short* vTh = (unsigned short*)(wsb + (32u << 20));
    unsigned short* vTl = (unsigned short*)(wsb + (40u << 20));
    float* p_ws  = (float*)(wsb + (48u << 20));                    // 16 MB
    unsigned short* oh = (unsigned short*)(wsb + (48u << 20));     // overlays p
    unsigned short* ol = (unsigned short*)(wsb + (56u << 20));
    float* alpha_ws = (float*)(wsb + (64u << 20));                 // 256 KB
    float* cen_ws   = (float*)(wsb + (64u << 20) + (256u << 10));
    float* c0_ws    = (float*)(wsb + (64u << 20) + (512u << 10));
    // stage-1 split scratch lives in the (not-yet-written) attn region
    unsigned short* ah = (unsigned short*)attn;                    // 8 MB
    unsigned short* al = ah + (size_t)MTOT * HIDN;                 // 8 MB
    unsigned short* wh = al + (size_t)MTOT * HIDN;                 // 2 MB
    unsigned short* wl = wh + (size_t)HIDN * HIDN;                 // 2 MB
    // Wo split reuses qh/ql space after attn_fused
    unsigned short* w2h = qh;
    unsigned short* w2l = ql;

    const dim3 blk(256);
    const dim3 gsplit_a(MTOT * HIDN / 8 / 256);
    const dim3 gsplit_w(16, 16);
    const dim3 ggemm(HIDN / 64, MTOT / 128);   // (16, 32) = 512 blocks

    // q = query @ Wq + bq -> qh/ql (bf16 only)
    split_w<<<gsplit_w, blk, 0, stream>>>(Wq, wh, wl);
    split_a<<<gsplit_a, blk, 0, stream>>>(query, ah, al);
    gemm_bf16x3<<<ggemm, blk, 0, stream>>>(ah, al, wh, wl, bq, nullptr, qh, ql, 0);
    // k -> kh/kl
    split_w<<<gsplit_w, blk, 0, stream>>>(Wk, wh, wl);
    split_a<<<gsplit_a, blk, 0, stream>>>(key_, ah, al);
    gemm_bf16x3<<<ggemm, blk, 0, stream>>>(ah, al, wh, wl, bk, nullptr, kh, kl, 0);
    // v -> vTh/vTl (per-head transposed)
    split_w<<<gsplit_w, blk, 0, stream>>>(Wv, wh, wl);
    split_a<<<gsplit_a, blk, 0, stream>>>(value, ah, al);
    gemm_bf16x3<<<ggemm, blk, 0, stream>>>(ah, al, wh, wl, bv, nullptr, vTh, vTl, 1);
    // p = q @ Wp + bp -> p_ws (f32); A is already-split qh/ql
    split_w<<<gsplit_w, blk, 0, stream>>>(Wp, wh, wl);
    gemm_bf16x3<<<ggemm, blk, 0, stream>>>(qh, ql, wh, wl, bp, p_ws, nullptr, nullptr, 0);
    // alpha + window params
    alpha_kernel<<<dim3(MTOT / 16), blk, 0, stream>>>(query, Wus, bus, alpha_ws);
    posparam_kernel<<<dim3((BATCH * NHEAD * S_LEN) / 256), blk, 0, stream>>>(
        p_ws, alpha_ws, Wup, bup, Wud, bud, cen_ws, c0_ws);
    // fused scores + softmax + attn-write + PV (1024 blocks, 64-row i-tiles)
    attn_fused<<<dim3(1024), blk, 0, stream>>>(
        qh, ql, kh, kl, vTh, vTl, cen_ws, c0_ws, attn, oh, ol);
    // x = o @ Wo + bo
    split_w<<<gsplit_w, blk, 0, stream>>>(Wo, w2h, w2l);
    gemm_bf16x3<<<ggemm, blk, 0, stream>>>(oh, ol, w2h, w2l, bo, x_out,
                                           nullptr, nullptr, 0);
}